// Round 10
// baseline (1667.807 us; speedup 1.0000x reference)
//
#include <hip/hip_runtime.h>
#include <hip/hip_fp16.h>
#include <math.h>

constexpr int DEPTH = 12;
constexpr int E     = 256;
constexpr int H     = 8;
constexpr int HD    = 32;
constexpr int N     = 257;
constexpr int B     = 64;
constexpr int BN    = B * N;      // 16448 = 257 * 64
constexpr int BNP   = 16512;      // 129 * 128 (token-padded for 128-token tiles)
constexpr int FFD   = 1024;
constexpr int UCNT  = 1000;
constexpr int Fdim  = 128;

enum { EPI_RESID = 1, EPI_GELU = 2, EPI_QKV = 3 };

typedef _Float16 f16x8 __attribute__((ext_vector_type(8)));
typedef _Float16 f16x4 __attribute__((ext_vector_type(4)));
typedef float    f32x4 __attribute__((ext_vector_type(4)));

__device__ __forceinline__ float gelu_exact(float z) {
  return 0.5f * z * (1.0f + erff(z * 0.70710678118654752440f));
}

#define GLOAD_LDS16(g, l) __builtin_amdgcn_global_load_lds( \
    (const __attribute__((address_space(1))) void*)(g),     \
    (__attribute__((address_space(3))) void*)(l), 16, 0, 0)

template<int NV>
__device__ __forceinline__ void wait_vmcnt() {
  asm volatile("s_waitcnt vmcnt(%0)" :: "i"(NV) : "memory");
}

// ---------- embed: x[b,n,e] fp32 = gathered + positions (LDS transpose, coalesced) ----------
__global__ __launch_bounds__(256) void embed_kernel(
    const int* __restrict__ user, const int* __restrict__ item,
    const float* __restrict__ utab, const float* __restrict__ itab,
    const float* __restrict__ pos, float* __restrict__ x)
{
  __shared__ float tile[32][33];
  const int tx = threadIdx.x, ty = threadIdx.y;   // (32, 8)
  const int b  = blockIdx.z;
  const int e0 = blockIdx.x * 32;                 // 8 tiles over E
  const int ft = blockIdx.y;                      // 0..3 user, 4..7 item
  const bool isU = (ft < 4);
  const int f0 = (ft & 3) * 32;
  const int id = isU ? user[b] : item[b];
  const float* tab = isU ? utab : itab;
  const int nbase = isU ? 1 : 1 + Fdim;
#pragma unroll
  for (int r = 0; r < 4; ++r) {
    const int e = ty + r * 8;
    tile[e][tx] = tab[((size_t)(e0 + e) * UCNT + id) * Fdim + f0 + tx];
  }
  __syncthreads();
#pragma unroll
  for (int r = 0; r < 4; ++r) {
    const int f = ty + r * 8;
    const int n = nbase + f0 + f;
    x[((size_t)b * N + n) * E + e0 + tx] = tile[tx][f] + pos[(size_t)n * E + e0 + tx];
  }
}

// ---------- cls row + zero h pad rows ----------
__global__ __launch_bounds__(256) void cls_pad_kernel(
    const float* __restrict__ cls, const float* __restrict__ pos,
    float* __restrict__ x, __half* __restrict__ h)
{
  const int t = blockIdx.x * 256 + threadIdx.x;   // 0..16383
  if (blockIdx.y == 0) {
    const int b = t >> 8, e = t & 255;
    x[((size_t)b * N) * E + e] = cls[e] + pos[e];
  } else {
    h[(size_t)BN * E + t] = __float2half(0.0f);   // 64 pad rows x 256
  }
}

// ---------- weight convert+transpose: fp32 (L,K,NC) -> fp16 [L][NCtot][K] at col ncoff ----------
__global__ __launch_bounds__(256) void convT_kernel(
    const float* __restrict__ in, __half* __restrict__ out,
    int K, int NC, int NCtot, int ncoff)
{
  __shared__ float tile[32][33];
  const int tx = threadIdx.x, ty = threadIdx.y;  // (32,8)
  const int n0 = blockIdx.x * 32, k0 = blockIdx.y * 32;
  const float* ip = in + (size_t)blockIdx.z * K * NC;
  __half* op = out + (size_t)blockIdx.z * NCtot * K;
#pragma unroll
  for (int r = 0; r < 4; ++r) {
    const int kk = ty + r * 8;
    tile[kk][tx] = ip[(size_t)(k0 + kk) * NC + n0 + tx];
  }
  __syncthreads();
#pragma unroll
  for (int r = 0; r < 4; ++r) {
    const int nn = ty + r * 8;
    op[(size_t)(ncoff + n0 + nn) * K + k0 + tx] = __float2half(tile[tx][nn]);
  }
}

// ---------- layernorm: wave per row; x fp32 in, h fp16 out ----------
__global__ __launch_bounds__(256) void ln_kernel(
    const float* __restrict__ x, __half* __restrict__ y,
    const float* __restrict__ g, const float* __restrict__ b)
{
  const int wave = threadIdx.x >> 6, lane = threadIdx.x & 63;
  const int row  = blockIdx.x * 4 + wave;
  const float4 v = *(const float4*)(x + (size_t)row * E + lane * 4);
  float s = v.x + v.y + v.z + v.w;
  float q = v.x * v.x + v.y * v.y + v.z * v.z + v.w * v.w;
#pragma unroll
  for (int o = 32; o > 0; o >>= 1) { s += __shfl_xor(s, o); q += __shfl_xor(q, o); }
  const float mean = s * (1.0f / 256.0f);
  const float var  = q * (1.0f / 256.0f) - mean * mean;
  const float rstd = rsqrtf(var + 1e-5f);
  const float4 gg = *(const float4*)(g + lane * 4);
  const float4 bb = *(const float4*)(b + lane * 4);
  __half2 h0 = __floats2half2_rn((v.x - mean) * rstd * gg.x + bb.x,
                                 (v.y - mean) * rstd * gg.y + bb.y);
  __half2 h1 = __floats2half2_rn((v.z - mean) * rstd * gg.z + bb.z,
                                 (v.w - mean) * rstd * gg.w + bb.w);
  __half2* yp = (__half2*)(y + (size_t)row * E + lane * 4);
  yp[0] = h0; yp[1] = h1;
}

// ---------- fp16 MFMA GEMM, C[out-col][token], depth-2 prefetch, 3 buffers ----------
// Round-6 lockstep (2 barriers/K-step, counted vmcnt never 0 in main loop,
// XOR source pre-swizzle, bijective XCD remap) + depth-2 DMA prefetch:
// STAGE(s+2) into buffer (s+2)%3; wait vmcnt(2*NDMA) keeps TWO steps of
// loads in flight, covering L2/HBM latency (~200-900cy) that depth-1's one
// compute step (~150-200cy) could not.  STAGE(s+2) overwrites the buffer
// read at step s-1, whose reads the end-of-step-(s-1) barrier already
// drained -> same safety argument as round 6.  K-loop fully unrolled so
// all buffer bases are compile-time constants.
template<int BMC, int BNT, int K, int NCOUT, int EPI, int NX>
__global__ __launch_bounds__(256) void gemm_f16(
    const __half* __restrict__ Act, const __half* __restrict__ Wt,
    const float* __restrict__ b0, const float* __restrict__ b1,
    const float* __restrict__ b2, void* __restrict__ outp)
{
  constexpr int MT = 4;
  constexpr int NT = BNT / 32;               // 4 or 2
  constexpr int ASW = (BMC / 16) / 4;        // 2
  constexpr int BSW = (BNT / 16) / 4;        // 2 or 1
  constexpr int NDMA = ASW + BSW;            // 4 or 3
  constexpr int AHALF = BMC * 32;
  constexpr int BHALF = BNT * 32;
  constexpr int BUF   = AHALF + BHALF;
  constexpr int NSTEP = K / 32;

  __shared__ __align__(16) __half smem[3 * BUF];   // 48 KB (QKV/FF) / 36 KB (RESID)

  const int t = threadIdx.x;
  const int wave = t >> 6, lane = t & 63;
  const int lm = lane & 15, lq = lane >> 4;

  // ---- bijective XCD remap ----
  const int wid = blockIdx.x;
  const int total = gridDim.x;
  const int q8 = total >> 3, r8 = total & 7;
  const int c = wid & 7, j = wid >> 3;
  const int lin = c * q8 + (c < r8 ? c : r8) + j;
  const int bx = lin % NX, by = lin / NX;
  const int col0 = bx * BMC;
  const int tok0 = by * BNT;

  const int srow = lane >> 2, sp = lane & 3;
  const __half* ag[ASW]; int aoff[ASW];
#pragma unroll
  for (int i = 0; i < ASW; ++i) {
    const int seg = wave * ASW + i;
    const int row = seg * 16 + srow;
    const int slot = sp ^ ((row >> 1) & 3);
    ag[i] = Wt + (size_t)(col0 + row) * K + slot * 8;
    aoff[i] = seg * 512;
  }
  const __half* bg[BSW]; int boff[BSW];
#pragma unroll
  for (int i = 0; i < BSW; ++i) {
    const int seg = wave * BSW + i;
    const int row = seg * 16 + srow;
    const int slot = sp ^ ((row >> 1) & 3);
    bg[i] = Act + (size_t)(tok0 + row) * K + slot * 8;
    boff[i] = seg * 512;
  }

  auto STAGE = [&](int step, int buf) {
    const int koff = step * 32;
    __half* base = smem + buf * BUF;
#pragma unroll
    for (int i = 0; i < ASW; ++i) GLOAD_LDS16(ag[i] + koff, base + aoff[i]);
#pragma unroll
    for (int i = 0; i < BSW; ++i) GLOAD_LDS16(bg[i] + koff, base + AHALF + boff[i]);
  };

  const int wm = (wave >> 1) * 64;         // out-col offset within tile
  const int wn = (wave & 1) * (BNT / 2);   // token offset within tile

  f32x4 acc[MT][NT];
#pragma unroll
  for (int i = 0; i < MT; ++i)
#pragma unroll
    for (int j2 = 0; j2 < NT; ++j2) acc[i][j2] = (f32x4){0.f, 0.f, 0.f, 0.f};

  STAGE(0, 0);
  if (NSTEP > 1) STAGE(1, 1);
#pragma unroll
  for (int s = 0; s < NSTEP; ++s) {
    if (s + 2 < NSTEP)      { STAGE(s + 2, (s + 2) % 3); wait_vmcnt<2 * NDMA>(); }
    else if (s + 1 < NSTEP) { wait_vmcnt<NDMA>(); }
    else                    { wait_vmcnt<0>(); }
    __builtin_amdgcn_s_barrier();
    asm volatile("" ::: "memory");

    const __half* As = smem + (s % 3) * BUF;
    const __half* Bs = As + AHALF;
    f16x8 af[MT], bf[NT];
#pragma unroll
    for (int mt = 0; mt < MT; ++mt) {
      const int row = wm + mt * 16 + lm;
      af[mt] = *(const f16x8*)&As[row * 32 + (lq ^ ((row >> 1) & 3)) * 8];
    }
#pragma unroll
    for (int nt = 0; nt < NT; ++nt) {
      const int row = wn + nt * 16 + lm;
      bf[nt] = *(const f16x8*)&Bs[row * 32 + (lq ^ ((row >> 1) & 3)) * 8];
    }
#pragma unroll
    for (int mt = 0; mt < MT; ++mt)
#pragma unroll
      for (int nt = 0; nt < NT; ++nt)
        acc[mt][nt] = __builtin_amdgcn_mfma_f32_16x16x32_f16(af[mt], bf[nt], acc[mt][nt], 0, 0, 0);

    if (s + 1 < NSTEP) {
      __builtin_amdgcn_s_barrier();
      asm volatile("" ::: "memory");
    }
  }

  // ---- epilogue straight from registers ----
  float br[MT][4];
#pragma unroll
  for (int mt = 0; mt < MT; ++mt) {
    const int cg = col0 + wm + mt * 16 + lq * 4;
    const float* bp;
    if constexpr (EPI == EPI_QKV) {
      const int tsel = cg >> 8;
      bp = (tsel == 0) ? b0 : (tsel == 1 ? b1 : b2);
      bp += (cg & 255);
    } else {
      bp = b0 + cg;
    }
    const float4 bv = *(const float4*)bp;
    br[mt][0] = bv.x; br[mt][1] = bv.y; br[mt][2] = bv.z; br[mt][3] = bv.w;
  }

#pragma unroll
  for (int nt = 0; nt < NT; ++nt) {
    const int token = tok0 + wn + nt * 16 + lm;
    if constexpr (EPI == EPI_RESID) {
      float* xrow = (float*)outp + (size_t)token * 256;
#pragma unroll
      for (int mt = 0; mt < MT; ++mt) {
        const int cg = col0 + wm + mt * 16 + lq * 4;
        float4 xv = *(float4*)(xrow + cg);
        xv.x += acc[mt][nt][0] + br[mt][0];
        xv.y += acc[mt][nt][1] + br[mt][1];
        xv.z += acc[mt][nt][2] + br[mt][2];
        xv.w += acc[mt][nt][3] + br[mt][3];
        *(float4*)(xrow + cg) = xv;
      }
    } else if constexpr (EPI == EPI_GELU) {
      if (token < BN) {
        __half* orow = (__half*)outp + (size_t)token * NCOUT;
#pragma unroll
        for (int mt = 0; mt < MT; ++mt) {
          const int cg = col0 + wm + mt * 16 + lq * 4;
          f16x4 hv;
#pragma unroll
          for (int r = 0; r < 4; ++r)
            hv[r] = (_Float16)gelu_exact(acc[mt][nt][r] + br[mt][r]);
          *(f16x4*)(orow + cg) = hv;
        }
      }
    } else {  // EPI_QKV
      if (token < BN) {
        const unsigned tu = (unsigned)token;
        const unsigned bb = tu / 257u;
        const unsigned nn = tu - bb * 257u;
#pragma unroll
        for (int mt = 0; mt < MT; ++mt) {
          const int cg = col0 + wm + mt * 16 + lq * 4;
          const int tsel = cg >> 8, rc = cg & 255;
          __half* dst = (__half*)outp + (size_t)tsel * (BN * 256)
                      + (((size_t)bb * H + (rc >> 5)) * N + nn) * HD + (rc & 31);
          f16x4 hv;
#pragma unroll
          for (int r = 0; r < 4; ++r)
            hv[r] = (_Float16)(acc[mt][nt][r] + br[mt][r]);
          *(f16x4*)dst = hv;
        }
      }
    }
  }
}

// ---------- MFMA flash attention: one block per bh, 8 waves (round-9 proven) ----------
__global__ __launch_bounds__(512) void attn_mfma(
    const __half* __restrict__ q, const __half* __restrict__ k,
    const __half* __restrict__ v, __half* __restrict__ o)
{
  __shared__ __align__(16) __half Ks[272][40];   // [key][hd]
  __shared__ __align__(16) __half Vt[32][280];   // [hd][key]

  const int bh = blockIdx.x;
  const int bb = bh >> 3, hh = bh & 7;
  const int t = threadIdx.x;
  const int wave = t >> 6, lane = t & 63;
  const int lm = lane & 15, lq = lane >> 4;

  const __half* kg = k + (size_t)bh * N * HD;
  const __half* vg = v + (size_t)bh * N * HD;

  const f16x8 zero8 = {0, 0, 0, 0, 0, 0, 0, 0};
  for (int i = t; i < 272 * 4; i += 512) {
    const int n = i >> 2, c8 = (i & 3) * 8;
    f16x8 kv = zero8, vv = zero8;
    if (n < N) {
      kv = *(const f16x8*)(kg + (size_t)n * HD + c8);
      vv = *(const f16x8*)(vg + (size_t)n * HD + c8);
    }
    *(f16x8*)&Ks[n][c8] = kv;
#pragma unroll
    for (int j = 0; j < 8; ++j) Vt[c8 + j][n] = vv[j];
  }
  __syncthreads();

  for (int ti = wave; ti < 17; ti += 8) {
    const int q0 = ti * 16;
    const int qg = q0 + lm;
    const int qrow = (qg < N) ? qg : (N - 1);   // clamp; discarded at store
    const f16x8 bq = *(const f16x8*)(q + ((size_t)bh * N + qrow) * HD + lq * 8);
    f32x4 Ot0 = {0.f, 0.f, 0.f, 0.f}, Ot1 = {0.f, 0.f, 0.f, 0.f};
    float mm = -3.0e38f, ll = 0.0f;

    for (int kt = 0; kt < 17; ++kt) {
      const int k0 = kt * 16;
      const f16x8 ak = *(const f16x8*)&Ks[k0 + lm][lq * 8];
      __builtin_amdgcn_s_setprio(1);
      f32x4 s = __builtin_amdgcn_mfma_f32_16x16x32_f16(ak, bq, (f32x4){0.f, 0.f, 0.f, 0.f}, 0, 0, 0);
      __builtin_amdgcn_s_setprio(0);
      if (k0 == 256) {  // mask padded keys (only key 256 valid)
        if (lq != 0) s[0] = -3.0e38f;
        s[1] = -3.0e38f; s[2] = -3.0e38f; s[3] = -3.0e38f;
      }
      float tm = fmaxf(fmaxf(s[0], s[1]), fmaxf(s[2], s[3]));
      tm = fmaxf(tm, __shfl_xor(tm, 16));
      tm = fmaxf(tm, __shfl_xor(tm, 32));
      const float mn    = fmaxf(mm, tm);
      const float alpha = __expf(mm - mn);
      const float p0 = __expf(s[0] - mn);
      const float p1 = __expf(s[1] - mn);
      const float p2 = __expf(s[2] - mn);
      const float p3 = __expf(s[3] - mn);
      float ts = p0 + p1 + p2 + p3;
      ts += __shfl_xor(ts, 16);
      ts += __shfl_xor(ts, 32);
      ll = ll * alpha + ts;
      Ot0 *= alpha;
      Ot1 *= alpha;
      const f16x4 pb = {(_Float16)p0, (_Float16)p1, (_Float16)p2, (_Float16)p3};
      const f16x4 av0 = *(const f16x4*)&Vt[lm][k0 + lq * 4];
      const f16x4 av1 = *(const f16x4*)&Vt[16 + lm][k0 + lq * 4];
      __builtin_amdgcn_s_setprio(1);
      Ot0 = __builtin_amdgcn_mfma_f32_16x16x16f16(av0, pb, Ot0, 0, 0, 0);
      Ot1 = __builtin_amdgcn_mfma_f32_16x16x16f16(av1, pb, Ot1, 0, 0, 0);
      __builtin_amdgcn_s_setprio(0);
      mm = mn;
    }

    const float inv = 1.0f / (16.0f * ll);
    if (qg < N) {
      __half* op = o + ((size_t)bb * N + qg) * E + hh * HD + lq * 4;
      __half2* p0 = (__half2*)op;
      p0[0] = __floats2half2_rn(Ot0[0] * inv, Ot0[1] * inv);
      p0[1] = __floats2half2_rn(Ot0[2] * inv, Ot0[3] * inv);
      __half2* p1 = (__half2*)(op + 16);
      p1[0] = __floats2half2_rn(Ot1[0] * inv, Ot1[1] * inv);
      p1[1] = __floats2half2_rn(Ot1[2] * inv, Ot1[3] * inv);
    }
  }
}

// ---------- head: mean over N, LN, dot ----------
__global__ __launch_bounds__(256) void head_kernel(
    const float* __restrict__ x, const float* __restrict__ g,
    const float* __restrict__ bb, const float* __restrict__ hw,
    const float* __restrict__ hbias, float* __restrict__ out)
{
  const int b = blockIdx.x;
  const int e = threadIdx.x;
  const float* xp = x + (size_t)b * N * E + e;
  float s = 0.0f;
  for (int n = 0; n < N; ++n) s += xp[(size_t)n * E];
  const float p = s / 257.0f;

  float ls = p, lq = p * p;
#pragma unroll
  for (int o = 32; o > 0; o >>= 1) { ls += __shfl_xor(ls, o); lq += __shfl_xor(lq, o); }
  __shared__ float sm[4], sv[4], sd[4];
  const int wv = e >> 6, ln = e & 63;
  if (ln == 0) { sm[wv] = ls; sv[wv] = lq; }
  __syncthreads();
  const float mean = (sm[0] + sm[1] + sm[2] + sm[3]) * (1.0f / 256.0f);
  const float var  = (sv[0] + sv[1] + sv[2] + sv[3]) * (1.0f / 256.0f) - mean * mean;
  const float y = (p - mean) * rsqrtf(var + 1e-5f) * g[e] + bb[e];
  float d = y * hw[e];
#pragma unroll
  for (int o = 32; o > 0; o >>= 1) d += __shfl_xor(d, o);
  if (ln == 0) sd[wv] = d;
  __syncthreads();
  if (e == 0) out[b] = sd[0] + sd[1] + sd[2] + sd[3] + hbias[0];
}

extern "C" void kernel_launch(void* const* d_in, const int* in_sizes, int n_in,
                              void* d_out, int out_size, void* d_ws, size_t ws_size,
                              hipStream_t stream)
{
  const int*   user = (const int*)d_in[0];
  const int*   item = (const int*)d_in[1];
  const float* utab = (const float*)d_in[2];
  const float* itab = (const float*)d_in[3];
  const float* cls  = (const float*)d_in[4];
  const float* pos  = (const float*)d_in[5];
  const float* ln1g = (const float*)d_in[6];
  const float* ln1b = (const float*)d_in[7];
  const float* Wq   = (const float*)d_in[8];
  const float* bq   = (const float*)d_in[9];
  const float* Wk   = (const float*)d_in[10];
  const float* bk   = (const float*)d_in[11];
  const float* Wv   = (const float*)d_in[12];
  const float* bv   = (const float*)d_in[13];
  const float* Wo   = (const float*)d_in[14];
  const float* bo   = (const float*)d_in[15];
  const float* ln2g = (const float*)d_in[16];
  const float* ln2b = (const float*)d_in[17];
  const float* W1   = (const float*)d_in[18];
  const float* b1   = (const float*)d_in[19];
  const float* W2   = (const float*)d_in[20];
  const float* b2   = (const float*)d_in[21];
  const float* hg   = (const float*)d_in[22];
  const float* hb   = (const float*)d_in[23];
  const float* hW   = (const float*)d_in[24];
  const float* hbias= (const float*)d_in[25];
  float* out = (float*)d_out;

  float*  x  = (float*)d_ws;                          // BN x 256 f32
  __half* h  = (__half*)(x + (size_t)BN * E);         // BNP x 256 f16 (token-padded)
  __half* fq = h + (size_t)BNP * E;                   // q|k|v (each BN*256); ff spans all
  __half* Wqkvt = fq + (size_t)BN * FFD;              // 12 x 768 x 256
  __half* Wot   = Wqkvt + (size_t)DEPTH * 768 * 256;  // 12 x 256 x 256
  __half* W1t   = Wot   + (size_t)DEPTH * 256 * 256;  // 12 x 1024 x 256
  __half* W2t   = W1t   + (size_t)DEPTH * 1024 * 256; // 12 x 256 x 1024
  __half* qb = fq;
  __half* kb = fq + (size_t)BN * 256;
  __half* vb = fq + (size_t)2 * BN * 256;

  convT_kernel<<<dim3(8, 8, DEPTH),  dim3(32, 8), 0, stream>>>(Wq, Wqkvt, 256, 256, 768, 0);
  convT_kernel<<<dim3(8, 8, DEPTH),  dim3(32, 8), 0, stream>>>(Wk, Wqkvt, 256, 256, 768, 256);
  convT_kernel<<<dim3(8, 8, DEPTH),  dim3(32, 8), 0, stream>>>(Wv, Wqkvt, 256, 256, 768, 512);
  convT_kernel<<<dim3(8, 8, DEPTH),  dim3(32, 8), 0, stream>>>(Wo, Wot, 256, 256, 256, 0);
  convT_kernel<<<dim3(32, 8, DEPTH), dim3(32, 8), 0, stream>>>(W1, W1t, 256, 1024, 1024, 0);
  convT_kernel<<<dim3(8, 32, DEPTH), dim3(32, 8), 0, stream>>>(W2, W2t, 1024, 256, 256, 0);

  cls_pad_kernel<<<dim3(64, 2), 256, 0, stream>>>(cls, pos, x, h);
  embed_kernel<<<dim3(8, 8, B), dim3(32, 8), 0, stream>>>(user, item, utab, itab, pos, x);

  for (int L = 0; L < DEPTH; ++L) {
    ln_kernel<<<BN / 4, 256, 0, stream>>>(x, h, ln1g + L * E, ln1b + L * E);
    gemm_f16<128, 128, 256, 768, EPI_QKV, 6><<<774, 256, 0, stream>>>(
        h, Wqkvt + (size_t)L * 768 * 256, bq + L * E, bk + L * E, bv + L * E, fq);
    attn_mfma<<<512, 512, 0, stream>>>(qb, kb, vb, h);
    gemm_f16<128, 64, 256, 256, EPI_RESID, 2><<<514, 256, 0, stream>>>(
        h, Wot + (size_t)L * 256 * 256, bo + L * E, nullptr, nullptr, x);
    ln_kernel<<<BN / 4, 256, 0, stream>>>(x, h, ln2g + L * E, ln2b + L * E);
    gemm_f16<128, 128, 256, 1024, EPI_GELU, 8><<<1032, 256, 0, stream>>>(
        h, W1t + (size_t)L * 1024 * 256, b1 + (size_t)L * FFD, nullptr, nullptr, fq);
    gemm_f16<128, 64, 1024, 256, EPI_RESID, 2><<<514, 256, 0, stream>>>(
        fq, W2t + (size_t)L * 256 * 1024, b2 + L * E, nullptr, nullptr, x);
  }

  head_kernel<<<B, 256, 0, stream>>>(x, hg, hb, hW, hbias, out);
}

// Round 11
// 1612.776 us; speedup vs baseline: 1.0341x; 1.0341x over previous
//
#include <hip/hip_runtime.h>
#include <hip/hip_fp16.h>
#include <math.h>

constexpr int DEPTH = 12;
constexpr int E     = 256;
constexpr int H     = 8;
constexpr int HD    = 32;
constexpr int N     = 257;
constexpr int B     = 64;
constexpr int BN    = B * N;      // 16448 = 257 * 64
constexpr int BNP   = 16512;      // 129 * 128 (token-padded for 128-token tiles)
constexpr int FFD   = 1024;
constexpr int UCNT  = 1000;
constexpr int Fdim  = 128;

enum { EPI_RESID = 1, EPI_GELU = 2, EPI_QKV = 3 };

typedef _Float16 f16x8 __attribute__((ext_vector_type(8)));
typedef _Float16 f16x4 __attribute__((ext_vector_type(4)));
typedef float    f32x4 __attribute__((ext_vector_type(4)));

__device__ __forceinline__ float gelu_exact(float z) {
  return 0.5f * z * (1.0f + erff(z * 0.70710678118654752440f));
}

#define GLOAD_LDS16(g, l) __builtin_amdgcn_global_load_lds( \
    (const __attribute__((address_space(1))) void*)(g),     \
    (__attribute__((address_space(3))) void*)(l), 16, 0, 0)

template<int NV>
__device__ __forceinline__ void wait_vmcnt() {
  asm volatile("s_waitcnt vmcnt(%0)" :: "i"(NV) : "memory");
}

// ---------- embed: x[b,n,e] fp32 = gathered + positions (LDS transpose, coalesced) ----------
__global__ __launch_bounds__(256) void embed_kernel(
    const int* __restrict__ user, const int* __restrict__ item,
    const float* __restrict__ utab, const float* __restrict__ itab,
    const float* __restrict__ pos, float* __restrict__ x)
{
  __shared__ float tile[32][33];
  const int tx = threadIdx.x, ty = threadIdx.y;   // (32, 8)
  const int b  = blockIdx.z;
  const int e0 = blockIdx.x * 32;                 // 8 tiles over E
  const int ft = blockIdx.y;                      // 0..3 user, 4..7 item
  const bool isU = (ft < 4);
  const int f0 = (ft & 3) * 32;
  const int id = isU ? user[b] : item[b];
  const float* tab = isU ? utab : itab;
  const int nbase = isU ? 1 : 1 + Fdim;
#pragma unroll
  for (int r = 0; r < 4; ++r) {
    const int e = ty + r * 8;
    tile[e][tx] = tab[((size_t)(e0 + e) * UCNT + id) * Fdim + f0 + tx];
  }
  __syncthreads();
#pragma unroll
  for (int r = 0; r < 4; ++r) {
    const int f = ty + r * 8;
    const int n = nbase + f0 + f;
    x[((size_t)b * N + n) * E + e0 + tx] = tile[tx][f] + pos[(size_t)n * E + e0 + tx];
  }
}

// ---------- cls row + zero h pad rows ----------
__global__ __launch_bounds__(256) void cls_pad_kernel(
    const float* __restrict__ cls, const float* __restrict__ pos,
    float* __restrict__ x, __half* __restrict__ h)
{
  const int t = blockIdx.x * 256 + threadIdx.x;   // 0..16383
  if (blockIdx.y == 0) {
    const int b = t >> 8, e = t & 255;
    x[((size_t)b * N) * E + e] = cls[e] + pos[e];
  } else {
    h[(size_t)BN * E + t] = __float2half(0.0f);   // 64 pad rows x 256
  }
}

// ---------- batched weight convert+transpose: all 6 weight groups in ONE dispatch ----------
// fp32 (L,K,NC) -> fp16 [L][NCtot][K] at col ncoff.  Flat block index decodes
// the group + tile; per-layer block count 768 (64+64+64+64+256+256).
__global__ __launch_bounds__(256) void convT_all(
    const float* __restrict__ Wq, const float* __restrict__ Wk,
    const float* __restrict__ Wv, const float* __restrict__ Wo,
    const float* __restrict__ W1, const float* __restrict__ W2,
    __half* __restrict__ Wqkvt, __half* __restrict__ Wot,
    __half* __restrict__ W1t,   __half* __restrict__ W2t)
{
  __shared__ float tile[32][33];
  const int tx = threadIdx.x, ty = threadIdx.y;  // (32,8)
  const int fb = blockIdx.x;                     // 0..767
  const int L  = blockIdx.y;

  const float* in; __half* out;
  int K, NC, NCtot, ncoff, n0, k0;
  if (fb < 192) {              // Wq / Wk / Wv -> Wqkvt (8x8 tiles each)
    const int w = fb >> 6, r = fb & 63;
    in = (w == 0) ? Wq : (w == 1 ? Wk : Wv);
    out = Wqkvt; K = 256; NC = 256; NCtot = 768; ncoff = w * 256;
    n0 = (r & 7) * 32; k0 = (r >> 3) * 32;
  } else if (fb < 256) {       // Wo (8x8)
    const int r = fb - 192;
    in = Wo; out = Wot; K = 256; NC = 256; NCtot = 256; ncoff = 0;
    n0 = (r & 7) * 32; k0 = (r >> 3) * 32;
  } else if (fb < 512) {       // W1 (32x8)
    const int r = fb - 256;
    in = W1; out = W1t; K = 256; NC = 1024; NCtot = 1024; ncoff = 0;
    n0 = (r & 31) * 32; k0 = (r >> 5) * 32;
  } else {                     // W2 (8x32)
    const int r = fb - 512;
    in = W2; out = W2t; K = 1024; NC = 256; NCtot = 256; ncoff = 0;
    n0 = (r & 7) * 32; k0 = (r >> 3) * 32;
  }
  const float* ip = in + (size_t)L * K * NC;
  __half* op = out + (size_t)L * NCtot * K;
#pragma unroll
  for (int r = 0; r < 4; ++r) {
    const int kk = ty + r * 8;
    tile[kk][tx] = ip[(size_t)(k0 + kk) * NC + n0 + tx];
  }
  __syncthreads();
#pragma unroll
  for (int r = 0; r < 4; ++r) {
    const int nn = ty + r * 8;
    op[(size_t)(ncoff + n0 + nn) * K + k0 + tx] = __float2half(tile[tx][nn]);
  }
}

// ---------- layernorm: wave per row; x fp32 in, h fp16 out ----------
__global__ __launch_bounds__(256) void ln_kernel(
    const float* __restrict__ x, __half* __restrict__ y,
    const float* __restrict__ g, const float* __restrict__ b)
{
  const int wave = threadIdx.x >> 6, lane = threadIdx.x & 63;
  const int row  = blockIdx.x * 4 + wave;
  const float4 v = *(const float4*)(x + (size_t)row * E + lane * 4);
  float s = v.x + v.y + v.z + v.w;
  float q = v.x * v.x + v.y * v.y + v.z * v.z + v.w * v.w;
#pragma unroll
  for (int o = 32; o > 0; o >>= 1) { s += __shfl_xor(s, o); q += __shfl_xor(q, o); }
  const float mean = s * (1.0f / 256.0f);
  const float var  = q * (1.0f / 256.0f) - mean * mean;
  const float rstd = rsqrtf(var + 1e-5f);
  const float4 gg = *(const float4*)(g + lane * 4);
  const float4 bb = *(const float4*)(b + lane * 4);
  __half2 h0 = __floats2half2_rn((v.x - mean) * rstd * gg.x + bb.x,
                                 (v.y - mean) * rstd * gg.y + bb.y);
  __half2 h1 = __floats2half2_rn((v.z - mean) * rstd * gg.z + bb.z,
                                 (v.w - mean) * rstd * gg.w + bb.w);
  __half2* yp = (__half2*)(y + (size_t)row * E + lane * 4);
  yp[0] = h0; yp[1] = h1;
}

// ---------- fp16 MFMA GEMM, C[out-col][token], 2-phase double-buffered ----------
// Round-6/9 proven structure (1622 us): 2 LDS buffers, 2 barriers/K-step,
// counted vmcnt (never 0 in main loop), XOR source pre-swizzle, bijective
// XCD chunk remap (y-major lin) so col-blocks sharing an activation tile
// land on one XCD's L2.  Depth>1 prefetch REGRESSED twice (r7 +46, r10 +46)
// — do not re-attempt without per-dispatch profiling.
template<int BMC, int BNT, int K, int NCOUT, int EPI, int NX>
__global__ __launch_bounds__(256) void gemm_f16(
    const __half* __restrict__ Act, const __half* __restrict__ Wt,
    const float* __restrict__ b0, const float* __restrict__ b1,
    const float* __restrict__ b2, void* __restrict__ outp)
{
  constexpr int MT = 4;
  constexpr int NT = BNT / 32;               // 4 or 2
  constexpr int ASW = (BMC / 16) / 4;        // 2
  constexpr int BSW = (BNT / 16) / 4;        // 2 or 1
  constexpr int NDMA = ASW + BSW;            // 4 or 3
  constexpr int AHALF = BMC * 32;
  constexpr int BHALF = BNT * 32;
  constexpr int BUF   = AHALF + BHALF;
  constexpr int NSTEP = K / 32;

  __shared__ __align__(16) __half smem[2 * BUF];

  const int t = threadIdx.x;
  const int wave = t >> 6, lane = t & 63;
  const int lm = lane & 15, lq = lane >> 4;

  // ---- bijective XCD remap ----
  const int wid = blockIdx.x;
  const int total = gridDim.x;
  const int q8 = total >> 3, r8 = total & 7;
  const int c = wid & 7, j = wid >> 3;
  const int lin = c * q8 + (c < r8 ? c : r8) + j;
  const int bx = lin % NX, by = lin / NX;
  const int col0 = bx * BMC;
  const int tok0 = by * BNT;

  const int srow = lane >> 2, sp = lane & 3;
  const __half* ag[ASW]; int aoff[ASW];
#pragma unroll
  for (int i = 0; i < ASW; ++i) {
    const int seg = wave * ASW + i;
    const int row = seg * 16 + srow;
    const int slot = sp ^ ((row >> 1) & 3);
    ag[i] = Wt + (size_t)(col0 + row) * K + slot * 8;
    aoff[i] = seg * 512;
  }
  const __half* bg[BSW]; int boff[BSW];
#pragma unroll
  for (int i = 0; i < BSW; ++i) {
    const int seg = wave * BSW + i;
    const int row = seg * 16 + srow;
    const int slot = sp ^ ((row >> 1) & 3);
    bg[i] = Act + (size_t)(tok0 + row) * K + slot * 8;
    boff[i] = seg * 512;
  }

  auto STAGE = [&](int step, int buf) {
    const int koff = step * 32;
    __half* base = smem + buf * BUF;
#pragma unroll
    for (int i = 0; i < ASW; ++i) GLOAD_LDS16(ag[i] + koff, base + aoff[i]);
#pragma unroll
    for (int i = 0; i < BSW; ++i) GLOAD_LDS16(bg[i] + koff, base + AHALF + boff[i]);
  };

  const int wm = (wave >> 1) * 64;         // out-col offset within tile
  const int wn = (wave & 1) * (BNT / 2);   // token offset within tile

  f32x4 acc[MT][NT];
#pragma unroll
  for (int i = 0; i < MT; ++i)
#pragma unroll
    for (int j2 = 0; j2 < NT; ++j2) acc[i][j2] = (f32x4){0.f, 0.f, 0.f, 0.f};

  STAGE(0, 0);
  for (int s = 0; s < NSTEP; ++s) {
    const int cur = s & 1;
    if (s + 1 < NSTEP) { STAGE(s + 1, cur ^ 1); wait_vmcnt<NDMA>(); }
    else               { wait_vmcnt<0>(); }
    __builtin_amdgcn_s_barrier();
    asm volatile("" ::: "memory");

    const __half* As = smem + cur * BUF;
    const __half* Bs = As + AHALF;
    f16x8 af[MT], bf[NT];
#pragma unroll
    for (int mt = 0; mt < MT; ++mt) {
      const int row = wm + mt * 16 + lm;
      af[mt] = *(const f16x8*)&As[row * 32 + (lq ^ ((row >> 1) & 3)) * 8];
    }
#pragma unroll
    for (int nt = 0; nt < NT; ++nt) {
      const int row = wn + nt * 16 + lm;
      bf[nt] = *(const f16x8*)&Bs[row * 32 + (lq ^ ((row >> 1) & 3)) * 8];
    }
#pragma unroll
    for (int mt = 0; mt < MT; ++mt)
#pragma unroll
      for (int nt = 0; nt < NT; ++nt)
        acc[mt][nt] = __builtin_amdgcn_mfma_f32_16x16x32_f16(af[mt], bf[nt], acc[mt][nt], 0, 0, 0);

    if (s + 1 < NSTEP) {
      __builtin_amdgcn_s_barrier();
      asm volatile("" ::: "memory");
    }
  }

  // ---- epilogue straight from registers ----
  float br[MT][4];
#pragma unroll
  for (int mt = 0; mt < MT; ++mt) {
    const int cg = col0 + wm + mt * 16 + lq * 4;
    const float* bp;
    if constexpr (EPI == EPI_QKV) {
      const int tsel = cg >> 8;
      bp = (tsel == 0) ? b0 : (tsel == 1 ? b1 : b2);
      bp += (cg & 255);
    } else {
      bp = b0 + cg;
    }
    const float4 bv = *(const float4*)bp;
    br[mt][0] = bv.x; br[mt][1] = bv.y; br[mt][2] = bv.z; br[mt][3] = bv.w;
  }

#pragma unroll
  for (int nt = 0; nt < NT; ++nt) {
    const int token = tok0 + wn + nt * 16 + lm;
    if constexpr (EPI == EPI_RESID) {
      float* xrow = (float*)outp + (size_t)token * 256;
#pragma unroll
      for (int mt = 0; mt < MT; ++mt) {
        const int cg = col0 + wm + mt * 16 + lq * 4;
        float4 xv = *(float4*)(xrow + cg);
        xv.x += acc[mt][nt][0] + br[mt][0];
        xv.y += acc[mt][nt][1] + br[mt][1];
        xv.z += acc[mt][nt][2] + br[mt][2];
        xv.w += acc[mt][nt][3] + br[mt][3];
        *(float4*)(xrow + cg) = xv;
      }
    } else if constexpr (EPI == EPI_GELU) {
      if (token < BN) {
        __half* orow = (__half*)outp + (size_t)token * NCOUT;
#pragma unroll
        for (int mt = 0; mt < MT; ++mt) {
          const int cg = col0 + wm + mt * 16 + lq * 4;
          f16x4 hv;
#pragma unroll
          for (int r = 0; r < 4; ++r)
            hv[r] = (_Float16)gelu_exact(acc[mt][nt][r] + br[mt][r]);
          *(f16x4*)(orow + cg) = hv;
        }
      }
    } else {  // EPI_QKV
      if (token < BN) {
        const unsigned tu = (unsigned)token;
        const unsigned bb = tu / 257u;
        const unsigned nn = tu - bb * 257u;
#pragma unroll
        for (int mt = 0; mt < MT; ++mt) {
          const int cg = col0 + wm + mt * 16 + lq * 4;
          const int tsel = cg >> 8, rc = cg & 255;
          __half* dst = (__half*)outp + (size_t)tsel * (BN * 256)
                      + (((size_t)bb * H + (rc >> 5)) * N + nn) * HD + (rc & 31);
          f16x4 hv;
#pragma unroll
          for (int r = 0; r < 4; ++r)
            hv[r] = (_Float16)(acc[mt][nt][r] + br[mt][r]);
          *(f16x4*)dst = hv;
        }
      }
    }
  }
}

// ---------- MFMA flash attention: one block per bh, 8 waves (round-9 proven) ----------
__global__ __launch_bounds__(512) void attn_mfma(
    const __half* __restrict__ q, const __half* __restrict__ k,
    const __half* __restrict__ v, __half* __restrict__ o)
{
  __shared__ __align__(16) __half Ks[272][40];   // [key][hd]
  __shared__ __align__(16) __half Vt[32][280];   // [hd][key]

  const int bh = blockIdx.x;
  const int bb = bh >> 3, hh = bh & 7;
  const int t = threadIdx.x;
  const int wave = t >> 6, lane = t & 63;
  const int lm = lane & 15, lq = lane >> 4;

  const __half* kg = k + (size_t)bh * N * HD;
  const __half* vg = v + (size_t)bh * N * HD;

  const f16x8 zero8 = {0, 0, 0, 0, 0, 0, 0, 0};
  for (int i = t; i < 272 * 4; i += 512) {
    const int n = i >> 2, c8 = (i & 3) * 8;
    f16x8 kv = zero8, vv = zero8;
    if (n < N) {
      kv = *(const f16x8*)(kg + (size_t)n * HD + c8);
      vv = *(const f16x8*)(vg + (size_t)n * HD + c8);
    }
    *(f16x8*)&Ks[n][c8] = kv;
#pragma unroll
    for (int j = 0; j < 8; ++j) Vt[c8 + j][n] = vv[j];
  }
  __syncthreads();

  for (int ti = wave; ti < 17; ti += 8) {
    const int q0 = ti * 16;
    const int qg = q0 + lm;
    const int qrow = (qg < N) ? qg : (N - 1);   // clamp; discarded at store
    const f16x8 bq = *(const f16x8*)(q + ((size_t)bh * N + qrow) * HD + lq * 8);
    f32x4 Ot0 = {0.f, 0.f, 0.f, 0.f}, Ot1 = {0.f, 0.f, 0.f, 0.f};
    float mm = -3.0e38f, ll = 0.0f;

    for (int kt = 0; kt < 17; ++kt) {
      const int k0 = kt * 16;
      const f16x8 ak = *(const f16x8*)&Ks[k0 + lm][lq * 8];
      __builtin_amdgcn_s_setprio(1);
      f32x4 s = __builtin_amdgcn_mfma_f32_16x16x32_f16(ak, bq, (f32x4){0.f, 0.f, 0.f, 0.f}, 0, 0, 0);
      __builtin_amdgcn_s_setprio(0);
      if (k0 == 256) {  // mask padded keys (only key 256 valid)
        if (lq != 0) s[0] = -3.0e38f;
        s[1] = -3.0e38f; s[2] = -3.0e38f; s[3] = -3.0e38f;
      }
      float tm = fmaxf(fmaxf(s[0], s[1]), fmaxf(s[2], s[3]));
      tm = fmaxf(tm, __shfl_xor(tm, 16));
      tm = fmaxf(tm, __shfl_xor(tm, 32));
      const float mn    = fmaxf(mm, tm);
      const float alpha = __expf(mm - mn);
      const float p0 = __expf(s[0] - mn);
      const float p1 = __expf(s[1] - mn);
      const float p2 = __expf(s[2] - mn);
      const float p3 = __expf(s[3] - mn);
      float ts = p0 + p1 + p2 + p3;
      ts += __shfl_xor(ts, 16);
      ts += __shfl_xor(ts, 32);
      ll = ll * alpha + ts;
      Ot0 *= alpha;
      Ot1 *= alpha;
      const f16x4 pb = {(_Float16)p0, (_Float16)p1, (_Float16)p2, (_Float16)p3};
      const f16x4 av0 = *(const f16x4*)&Vt[lm][k0 + lq * 4];
      const f16x4 av1 = *(const f16x4*)&Vt[16 + lm][k0 + lq * 4];
      __builtin_amdgcn_s_setprio(1);
      Ot0 = __builtin_amdgcn_mfma_f32_16x16x16f16(av0, pb, Ot0, 0, 0, 0);
      Ot1 = __builtin_amdgcn_mfma_f32_16x16x16f16(av1, pb, Ot1, 0, 0, 0);
      __builtin_amdgcn_s_setprio(0);
      mm = mn;
    }

    const float inv = 1.0f / (16.0f * ll);
    if (qg < N) {
      __half* op = o + ((size_t)bb * N + qg) * E + hh * HD + lq * 4;
      __half2* p0 = (__half2*)op;
      p0[0] = __floats2half2_rn(Ot0[0] * inv, Ot0[1] * inv);
      p0[1] = __floats2half2_rn(Ot0[2] * inv, Ot0[3] * inv);
      __half2* p1 = (__half2*)(op + 16);
      p1[0] = __floats2half2_rn(Ot1[0] * inv, Ot1[1] * inv);
      p1[1] = __floats2half2_rn(Ot1[2] * inv, Ot1[3] * inv);
    }
  }
}

// ---------- head: mean over N, LN, dot ----------
__global__ __launch_bounds__(256) void head_kernel(
    const float* __restrict__ x, const float* __restrict__ g,
    const float* __restrict__ bb, const float* __restrict__ hw,
    const float* __restrict__ hbias, float* __restrict__ out)
{
  const int b = blockIdx.x;
  const int e = threadIdx.x;
  const float* xp = x + (size_t)b * N * E + e;
  float s = 0.0f;
  for (int n = 0; n < N; ++n) s += xp[(size_t)n * E];
  const float p = s / 257.0f;

  float ls = p, lq = p * p;
#pragma unroll
  for (int o = 32; o > 0; o >>= 1) { ls += __shfl_xor(ls, o); lq += __shfl_xor(lq, o); }
  __shared__ float sm[4], sv[4], sd[4];
  const int wv = e >> 6, ln = e & 63;
  if (ln == 0) { sm[wv] = ls; sv[wv] = lq; }
  __syncthreads();
  const float mean = (sm[0] + sm[1] + sm[2] + sm[3]) * (1.0f / 256.0f);
  const float var  = (sv[0] + sv[1] + sv[2] + sv[3]) * (1.0f / 256.0f) - mean * mean;
  const float y = (p - mean) * rsqrtf(var + 1e-5f) * g[e] + bb[e];
  float d = y * hw[e];
#pragma unroll
  for (int o = 32; o > 0; o >>= 1) d += __shfl_xor(d, o);
  if (ln == 0) sd[wv] = d;
  __syncthreads();
  if (e == 0) out[b] = sd[0] + sd[1] + sd[2] + sd[3] + hbias[0];
}

extern "C" void kernel_launch(void* const* d_in, const int* in_sizes, int n_in,
                              void* d_out, int out_size, void* d_ws, size_t ws_size,
                              hipStream_t stream)
{
  const int*   user = (const int*)d_in[0];
  const int*   item = (const int*)d_in[1];
  const float* utab = (const float*)d_in[2];
  const float* itab = (const float*)d_in[3];
  const float* cls  = (const float*)d_in[4];
  const float* pos  = (const float*)d_in[5];
  const float* ln1g = (const float*)d_in[6];
  const float* ln1b = (const float*)d_in[7];
  const float* Wq   = (const float*)d_in[8];
  const float* bq   = (const float*)d_in[9];
  const float* Wk   = (const float*)d_in[10];
  const float* bk   = (const float*)d_in[11];
  const float* Wv   = (const float*)d_in[12];
  const float* bv   = (const float*)d_in[13];
  const float* Wo   = (const float*)d_in[14];
  const float* bo   = (const float*)d_in[15];
  const float* ln2g = (const float*)d_in[16];
  const float* ln2b = (const float*)d_in[17];
  const float* W1   = (const float*)d_in[18];
  const float* b1   = (const float*)d_in[19];
  const float* W2   = (const float*)d_in[20];
  const float* b2   = (const float*)d_in[21];
  const float* hg   = (const float*)d_in[22];
  const float* hb   = (const float*)d_in[23];
  const float* hW   = (const float*)d_in[24];
  const float* hbias= (const float*)d_in[25];
  float* out = (float*)d_out;

  float*  x  = (float*)d_ws;                          // BN x 256 f32
  __half* h  = (__half*)(x + (size_t)BN * E);         // BNP x 256 f16 (token-padded)
  __half* fq = h + (size_t)BNP * E;                   // q|k|v (each BN*256); ff spans all
  __half* Wqkvt = fq + (size_t)BN * FFD;              // 12 x 768 x 256
  __half* Wot   = Wqkvt + (size_t)DEPTH * 768 * 256;  // 12 x 256 x 256
  __half* W1t   = Wot   + (size_t)DEPTH * 256 * 256;  // 12 x 1024 x 256
  __half* W2t   = W1t   + (size_t)DEPTH * 1024 * 256; // 12 x 256 x 1024
  __half* qb = fq;
  __half* kb = fq + (size_t)BN * 256;
  __half* vb = fq + (size_t)2 * BN * 256;

  convT_all<<<dim3(768, DEPTH), dim3(32, 8), 0, stream>>>(
      Wq, Wk, Wv, Wo, W1, W2, Wqkvt, Wot, W1t, W2t);

  cls_pad_kernel<<<dim3(64, 2), 256, 0, stream>>>(cls, pos, x, h);
  embed_kernel<<<dim3(8, 8, B), dim3(32, 8), 0, stream>>>(user, item, utab, itab, pos, x);

  for (int L = 0; L < DEPTH; ++L) {
    ln_kernel<<<BN / 4, 256, 0, stream>>>(x, h, ln1g + L * E, ln1b + L * E);
    gemm_f16<128, 128, 256, 768, EPI_QKV, 6><<<774, 256, 0, stream>>>(
        h, Wqkvt + (size_t)L * 768 * 256, bq + L * E, bk + L * E, bv + L * E, fq);
    attn_mfma<<<512, 512, 0, stream>>>(qb, kb, vb, h);
    gemm_f16<128, 64, 256, 256, EPI_RESID, 2><<<514, 256, 0, stream>>>(
        h, Wot + (size_t)L * 256 * 256, bo + L * E, nullptr, nullptr, x);
    ln_kernel<<<BN / 4, 256, 0, stream>>>(x, h, ln2g + L * E, ln2b + L * E);
    gemm_f16<128, 128, 256, 1024, EPI_GELU, 8><<<1032, 256, 0, stream>>>(
        h, W1t + (size_t)L * 1024 * 256, b1 + (size_t)L * FFD, nullptr, nullptr, fq);
    gemm_f16<128, 64, 1024, 256, EPI_RESID, 2><<<514, 256, 0, stream>>>(
        fq, W2t + (size_t)L * 256 * 1024, b2 + L * E, nullptr, nullptr, x);
  }

  head_kernel<<<B, 256, 0, stream>>>(x, hg, hb, hW, hbias, out);
}